// Round 6
// baseline (1015.221 us; speedup 1.0000x reference)
//
#include <hip/hip_runtime.h>

// CfC cell, fp16-MFMA implementation.
//   h   = 1.7159*tanh(0.666*(concat(input,hx) @ Wb^T + bb))   [B,1024]
//   ff1 = tanh(h@W1^T+b1), ff2 = tanh(h@W2^T+b2)
//   t   = sigmoid((h@Wa^T+ba)*ts + (h@Wt^T+bt))
//   out = ff1 + t*(ff2-ff1)                                   [B,512]
// Round 6: occupancy-first redesign. B-operands come straight from global
// (L2-resident weight slices) into reg double-buffers; LDS holds only A
// (3 x 8 KB) -> 6 blocks/CU, 24 waves/CU of INDEPENDENT blocks (m114
// regime). One barrier + counted vmcnt(2) per K-step. Round-3-verified
// zero-conflict chunk-XOR swizzle ((r>>1)&3 bits) on A staging/reads.

typedef _Float16 f16;
typedef _Float16 f16x8 __attribute__((ext_vector_type(8)));
typedef _Float16 f16x4 __attribute__((ext_vector_type(4)));
typedef float f32x4 __attribute__((ext_vector_type(4)));

static constexpr int B_ = 16384, IN_ = 256, HID_ = 512, UNITS_ = 1024, CAT_ = 768;

__device__ __forceinline__ void gload_lds16(const void* g, void* l) {
  __builtin_amdgcn_global_load_lds(
      (const __attribute__((address_space(1))) void*)g,
      (__attribute__((address_space(3))) void*)l, 16, 0, 0);
}

#define MFMA16(a, b, c) __builtin_amdgcn_mfma_f32_16x16x32_f16((a), (b), (c), 0, 0, 0)

// ---- conversion kernels -------------------------------------------------

__global__ void build_x_kernel(const float* __restrict__ inp,
                               const float* __restrict__ hx,
                               f16* __restrict__ x) {
  const int per_row = CAT_ / 4;
  int gid = blockIdx.x * blockDim.x + threadIdx.x;
  if (gid >= B_ * per_row) return;
  int b = gid / per_row, j = gid - b * per_row;
  float4 v;
  if (j < IN_ / 4) v = ((const float4*)(inp + (size_t)b * IN_))[j];
  else             v = ((const float4*)(hx  + (size_t)b * HID_))[j - IN_ / 4];
  f16x4 o = {(f16)v.x, (f16)v.y, (f16)v.z, (f16)v.w};
  *((f16x4*)(x + (size_t)b * CAT_ + j * 4)) = o;
}

__global__ void cvt_all_kernel(const float* __restrict__ Wb,
                               const float* __restrict__ W1,
                               const float* __restrict__ W2,
                               const float* __restrict__ Wa,
                               const float* __restrict__ Wt,
                               f16* __restrict__ dWb, f16* __restrict__ dWh) {
  const int seg = blockIdx.y;
  const int i = blockIdx.x * blockDim.x + threadIdx.x;
  const float* s;
  f16* d;
  int n4;
  if (seg == 0) {
    s = Wb; d = dWb; n4 = UNITS_ * CAT_ / 4;
  } else {
    const float* srcs[4] = {W1, W2, Wa, Wt};
    s = srcs[seg - 1];
    d = dWh + (size_t)(seg - 1) * HID_ * UNITS_;
    n4 = HID_ * UNITS_ / 4;
  }
  if (i >= n4) return;
  float4 v = ((const float4*)s)[i];
  f16x4 o = {(f16)v.x, (f16)v.y, (f16)v.z, (f16)v.w};
  ((f16x4*)d)[i] = o;
}

// ---- GEMM1: h = lecun_tanh(X @ Wb^T + bb) ------------------------------
// 1024 blocks (rb=bid>>3 over 128 row-tiles, cb=bid&7 over 8 col-tiles).
// 256 thr / 4 waves; wave = 128 rows x 32 cols. A in LDS (3x8KB), B (Wb)
// direct from global to regs (L2-resident 192 KB slice per XCD).

__global__ __launch_bounds__(256, 6) void gemm1_kernel(
    const f16* __restrict__ X, const f16* __restrict__ Wb,
    const float* __restrict__ bb, f16* __restrict__ H) {
  constexpr int BK = 32, K = CAT_, N = UNITS_;
  constexpr int NT = K / BK;  // 24
  __shared__ f16 As[3][128 * BK];  // 24 KB
  const int t = threadIdx.x;
  const int lane = t & 63, wc = t >> 6;
  const int cb = blockIdx.x & 7, rb = blockIdx.x >> 3;
  const int arow0 = rb * 128, bcol0 = cb * 128;

  f32x4 acc[8][2] = {};

  // A staging: thread t -> row (t>>2) [+64 for call 1], phys chunk t&3.
  const int schunk = ((t & 3) ^ ((t >> 3) & 3)) * 8;
  const f16* aP0 = X + (size_t)(arow0 + (t >> 2)) * K + schunk;
  const f16* aP1 = X + (size_t)(arow0 + 64 + (t >> 2)) * K + schunk;
  const int l8 = t * 8;

  const int fr = lane & 15;
  const int klo = lane >> 4;
  const int ksw = (klo ^ ((lane >> 1) & 3)) * 8;  // verified zero-conflict

  const f16* bB0 = Wb + (size_t)(bcol0 + wc * 32 + fr) * K + klo * 8;
  const f16* bB1 = Wb + (size_t)(bcol0 + wc * 32 + 16 + fr) * K + klo * 8;

#define STAGE1(buf, k0)                                  \
  do {                                                   \
    gload_lds16(aP0 + (k0), &As[buf][l8]);               \
    gload_lds16(aP1 + (k0), &As[buf][2048 + l8]);        \
  } while (0)

  STAGE1(0, 0);
  STAGE1(1, BK);
  f16x8 bCur0 = *((const f16x8*)(bB0));
  f16x8 bCur1 = *((const f16x8*)(bB1));

  for (int tt = 0; tt < NT; ++tt) {
    const int cur = tt % 3;
    if (tt + 1 < NT) asm volatile("s_waitcnt vmcnt(2)" ::: "memory");
    else             asm volatile("s_waitcnt vmcnt(0)" ::: "memory");
    __builtin_amdgcn_s_barrier();
    asm volatile("" ::: "memory");
    f16x8 aF[8];
#pragma unroll
    for (int m = 0; m < 8; ++m)
      aF[m] = *((const f16x8*)(&As[cur][(m * 16 + fr) * BK + ksw]));
    f16x8 bN0, bN1;
    if (tt + 1 < NT) {
      bN0 = *((const f16x8*)(bB0 + (tt + 1) * BK));
      bN1 = *((const f16x8*)(bB1 + (tt + 1) * BK));
    }
    if (tt + 2 < NT) STAGE1((tt + 2) % 3, (tt + 2) * BK);
#pragma unroll
    for (int m = 0; m < 8; ++m) {
      acc[m][0] = MFMA16(aF[m], bCur0, acc[m][0]);
      acc[m][1] = MFMA16(aF[m], bCur1, acc[m][1]);
    }
    if (tt + 1 < NT) { bCur0 = bN0; bCur1 = bN1; }
  }
#undef STAGE1

#pragma unroll
  for (int n = 0; n < 2; ++n) {
    const int colg = bcol0 + wc * 32 + n * 16 + fr;
    const float bias = bb[colg];
#pragma unroll
    for (int m = 0; m < 8; ++m)
#pragma unroll
      for (int i = 0; i < 4; ++i) {
        const int rowg = arow0 + m * 16 + klo * 4 + i;
        float v = acc[m][n][i] + bias;
        v = 1.7159f * tanhf(0.666f * v);
        H[(size_t)rowg * N + colg] = (f16)v;
      }
  }
}

// ---- GEMM2: four heads fused --------------------------------------------
// 1024 blocks (rb 0..127 x cb 0..7). 256 thr / 4 waves; wave = 128 rows x
// 16 cols x 4 heads (acc[8][4]). A in LDS (3x8KB), B (4 head slices, 512 KB
// per XCD) direct from global to reg double-buffer.

__global__ __launch_bounds__(256, 6) void gemm2_kernel(
    const f16* __restrict__ H, const f16* __restrict__ W,
    const float* __restrict__ b1, const float* __restrict__ b2,
    const float* __restrict__ ba, const float* __restrict__ bt,
    const float* __restrict__ ts, float* __restrict__ out) {
  constexpr int BK = 32, K = UNITS_;
  constexpr int NT = K / BK;  // 32
  __shared__ f16 As[3][128 * BK];  // 24 KB
  const int t = threadIdx.x;
  const int lane = t & 63, wc = t >> 6;
  const int cb = blockIdx.x & 7, rb = blockIdx.x >> 3;
  const int arow0 = rb * 128, bcol0 = cb * 64;

  f32x4 acc[8][4] = {};  // [m][head]

  const int schunk = ((t & 3) ^ ((t >> 3) & 3)) * 8;
  const f16* aP0 = H + (size_t)(arow0 + (t >> 2)) * K + schunk;
  const f16* aP1 = H + (size_t)(arow0 + 64 + (t >> 2)) * K + schunk;
  const int l8 = t * 8;

  const int fr = lane & 15;
  const int klo = lane >> 4;
  const int ksw = (klo ^ ((lane >> 1) & 3)) * 8;

  const f16* bB[4];
#pragma unroll
  for (int h = 0; h < 4; ++h)
    bB[h] = W + (size_t)(h * HID_ + bcol0 + wc * 16 + fr) * K + klo * 8;

#define STAGE2(buf, k0)                                  \
  do {                                                   \
    gload_lds16(aP0 + (k0), &As[buf][l8]);               \
    gload_lds16(aP1 + (k0), &As[buf][2048 + l8]);        \
  } while (0)

  STAGE2(0, 0);
  STAGE2(1, BK);
  f16x8 bCur[4];
#pragma unroll
  for (int h = 0; h < 4; ++h) bCur[h] = *((const f16x8*)(bB[h]));

  for (int tt = 0; tt < NT; ++tt) {
    const int cur = tt % 3;
    if (tt + 1 < NT) asm volatile("s_waitcnt vmcnt(2)" ::: "memory");
    else             asm volatile("s_waitcnt vmcnt(0)" ::: "memory");
    __builtin_amdgcn_s_barrier();
    asm volatile("" ::: "memory");
    f16x8 aF[8];
#pragma unroll
    for (int m = 0; m < 8; ++m)
      aF[m] = *((const f16x8*)(&As[cur][(m * 16 + fr) * BK + ksw]));
    f16x8 bN[4];
    if (tt + 1 < NT) {
#pragma unroll
      for (int h = 0; h < 4; ++h)
        bN[h] = *((const f16x8*)(bB[h] + (tt + 1) * BK));
    }
    if (tt + 2 < NT) STAGE2((tt + 2) % 3, (tt + 2) * BK);
#pragma unroll
    for (int m = 0; m < 8; ++m)
#pragma unroll
      for (int h = 0; h < 4; ++h)
        acc[m][h] = MFMA16(aF[m], bCur[h], acc[m][h]);
    if (tt + 1 < NT) {
#pragma unroll
      for (int h = 0; h < 4; ++h) bCur[h] = bN[h];
    }
  }
#undef STAGE2

  const int colg = bcol0 + wc * 16 + fr;
  const float B1 = b1[colg], B2 = b2[colg], BA = ba[colg], BT = bt[colg];
#pragma unroll
  for (int m = 0; m < 8; ++m) {
#pragma unroll
    for (int i = 0; i < 4; ++i) {
      const int rowg = arow0 + m * 16 + klo * 4 + i;
      const float ff1 = tanhf(acc[m][0][i] + B1);
      const float ff2 = tanhf(acc[m][1][i] + B2);
      const float ta = acc[m][2][i] + BA;
      const float tb = acc[m][3][i] + BT;
      const float z = ta * ts[rowg] + tb;
      const float ti = 1.0f / (1.0f + __expf(-z));
      out[(size_t)rowg * HID_ + colg] = ff1 + ti * (ff2 - ff1);
    }
  }
}

// ---- launch -------------------------------------------------------------

extern "C" void kernel_launch(void* const* d_in, const int* in_sizes, int n_in,
                              void* d_out, int out_size, void* d_ws, size_t ws_size,
                              hipStream_t stream) {
  const float* input = (const float*)d_in[0];
  const float* hx    = (const float*)d_in[1];
  const float* ts    = (const float*)d_in[2];
  const float* Wb    = (const float*)d_in[3];
  const float* bb    = (const float*)d_in[4];
  const float* W1    = (const float*)d_in[5];
  const float* b1    = (const float*)d_in[6];
  const float* W2    = (const float*)d_in[7];
  const float* b2    = (const float*)d_in[8];
  const float* Wa    = (const float*)d_in[9];
  const float* ba    = (const float*)d_in[10];
  const float* Wt    = (const float*)d_in[11];
  const float* bt    = (const float*)d_in[12];
  float* out = (float*)d_out;

  char* ws = (char*)d_ws;
  f16* x_f16  = (f16*)ws;  ws += (size_t)B_ * CAT_ * 2;
  f16* h_f16  = (f16*)ws;  ws += (size_t)B_ * UNITS_ * 2;
  f16* Wb_f16 = (f16*)ws;  ws += (size_t)UNITS_ * CAT_ * 2;
  f16* Wh_f16 = (f16*)ws;  ws += (size_t)4 * HID_ * UNITS_ * 2;

  build_x_kernel<<<(B_ * (CAT_ / 4) + 255) / 256, 256, 0, stream>>>(input, hx, x_f16);
  cvt_all_kernel<<<dim3((UNITS_ * CAT_ / 4 + 255) / 256, 5), 256, 0, stream>>>(
      Wb, W1, W2, Wa, Wt, Wb_f16, Wh_f16);

  gemm1_kernel<<<dim3(1024), 256, 0, stream>>>(x_f16, Wb_f16, bb, h_f16);
  gemm2_kernel<<<dim3(1024), 256, 0, stream>>>(h_f16, Wh_f16, b1, b2, ba, bt, ts, out);
}

// Round 7
// 158.353 us; speedup vs baseline: 6.4111x; 6.4111x over previous
//
#include <hip/hip_runtime.h>

// CfC cell, fp16-MFMA implementation.
//   h   = 1.7159*tanh(0.666*(concat(input,hx) @ Wb^T + bb))   [B,1024]
//   ff1 = tanh(h@W1^T+b1), ff2 = tanh(h@W2^T+b2)
//   t   = sigmoid((h@Wa^T+ba)*ts + (h@Wt^T+bt))
//   out = ff1 + t*(ff2-ff1)                                   [B,512]
// Round 7: both GEMMs on a correctly-derived m201-style 4-phase template:
// 256x256 tile, BK=64, 512 thr / 8 waves as 4M x 2N (per-wave 64 rows x
// two 64-col sets spanning BOTH B-LDS halves -> staggered half consumption
// -> vmcnt(2) twice per K-tile is race-free with >=2-phase prefetch lead).
// 128 KB LDS (2 dbuf x 2 half x 128x64 x A,B). Verified 3-bit chunk-XOR
// swizzle (zero conflicts, r4). gemm2 B is head-interleaved by the cvt
// kernel (n' = q*64 + h*16 + r) so frag n == head and the epilogue fuses.
// Round-6 lesson: __launch_bounds__ 2nd arg is waves/EU -> (512,2) = 256
// VGPR cap; est. usage ~230, no spill (watch WRITE_SIZE).

typedef _Float16 f16;
typedef _Float16 f16x8 __attribute__((ext_vector_type(8)));
typedef _Float16 f16x4 __attribute__((ext_vector_type(4)));
typedef float f32x4 __attribute__((ext_vector_type(4)));

static constexpr int B_ = 16384, IN_ = 256, HID_ = 512, UNITS_ = 1024, CAT_ = 768;

__device__ __forceinline__ void gload_lds16(const void* g, void* l) {
  __builtin_amdgcn_global_load_lds(
      (const __attribute__((address_space(1))) void*)g,
      (__attribute__((address_space(3))) void*)l, 16, 0, 0);
}

#define MFMA16(a, b, c) __builtin_amdgcn_mfma_f32_16x16x32_f16((a), (b), (c), 0, 0, 0)
#define BARRIER() do { asm volatile("" ::: "memory"); __builtin_amdgcn_s_barrier(); asm volatile("" ::: "memory"); } while (0)

// ---- conversion kernels -------------------------------------------------

__global__ void build_x_kernel(const float* __restrict__ inp,
                               const float* __restrict__ hx,
                               f16* __restrict__ x) {
  const int per_row = CAT_ / 4;
  int gid = blockIdx.x * blockDim.x + threadIdx.x;
  if (gid >= B_ * per_row) return;
  int b = gid / per_row, j = gid - b * per_row;
  float4 v;
  if (j < IN_ / 4) v = ((const float4*)(inp + (size_t)b * IN_))[j];
  else             v = ((const float4*)(hx  + (size_t)b * HID_))[j - IN_ / 4];
  f16x4 o = {(f16)v.x, (f16)v.y, (f16)v.z, (f16)v.w};
  *((f16x4*)(x + (size_t)b * CAT_ + j * 4)) = o;
}

// seg 0: Wb [1024][768] linear cast.
// seg 1: Wh head-interleaved: dWh row n' = W_h row c, h=(n'>>4)&3,
//        c = ((n'>>6)<<4) | (n'&15).   n' in [0,2048).
__global__ void cvt_all_kernel(const float* __restrict__ Wb,
                               const float* __restrict__ W1,
                               const float* __restrict__ W2,
                               const float* __restrict__ Wa,
                               const float* __restrict__ Wt,
                               f16* __restrict__ dWb, f16* __restrict__ dWh) {
  const int seg = blockIdx.y;
  const int i = blockIdx.x * blockDim.x + threadIdx.x;
  if (seg == 0) {
    if (i >= UNITS_ * CAT_ / 4) return;
    float4 v = ((const float4*)Wb)[i];
    f16x4 o = {(f16)v.x, (f16)v.y, (f16)v.z, (f16)v.w};
    ((f16x4*)dWb)[i] = o;
  } else {
    if (i >= 2048 * (UNITS_ / 4)) return;
    const int np = i >> 8;          // n' row (1024/4 = 256 groups per row)
    const int k4 = i & 255;
    const int h = (np >> 4) & 3;
    const int c = ((np >> 6) << 4) | (np & 15);
    const float* srcs[4] = {W1, W2, Wa, Wt};
    float4 v = *((const float4*)(srcs[h] + (size_t)c * UNITS_ + k4 * 4));
    f16x4 o = {(f16)v.x, (f16)v.y, (f16)v.z, (f16)v.w};
    *((f16x4*)(dWh + (size_t)np * UNITS_ + k4 * 4)) = o;
  }
}

// ---- GEMM1: h = lecun_tanh(X @ Wb^T + bb) ------------------------------
// M=16384 N=1024 K=768. Grid 64x4 = 256 blocks. 256x256 tile, NT=12.

__global__ __launch_bounds__(512, 2) void gemm1_kernel(
    const f16* __restrict__ X, const f16* __restrict__ Wb,
    const float* __restrict__ bb, f16* __restrict__ H) {
  constexpr int K = CAT_, BK = 64, NT = K / BK;  // 12
  __shared__ f16 As[2][2][8192];  // [dbuf][half][128*64]
  __shared__ f16 Bs[2][2][8192];
  const int t = threadIdx.x;
  const int lane = t & 63, wid = t >> 6;
  const int wr = wid >> 1;          // 0..3 (64-row band)
  const int wc = wid & 1;           // 0..1
  const int bc = blockIdx.x & 3, br = blockIdx.x >> 2;
  const int arow0 = br * 256;
  const int bn0 = bc * 256;

  f32x4 acc[4][8] = {};  // [m 0..3][set*4 + n]

  const int tr = t >> 3;                         // 0..63
  const int sch = ((t & 7) ^ (tr & 7)) * 8;      // pre-swizzled src chunk
  const f16* aSrc = X + (size_t)(arow0 + tr) * K + sch;
  const f16* bSrc = Wb + (size_t)(bn0 + tr) * K + sch;

  const int fr = lane & 15, klo = lane >> 4;
  const int cs0 = (klo ^ (fr & 7)) * 8;          // kk=0 phys chunk (f16 off)
  const int cs1 = ((klo + 4) ^ (fr & 7)) * 8;    // kk=1

#define SA(d, h, q, kt) gload_lds16(aSrc + (size_t)((h) * 128 + (q) * 64) * K + (kt) * BK, &As[d][h][(q) * 4096 + t * 8])
#define SB(d, h, q, kt) gload_lds16(bSrc + (size_t)((h) * 128 + (q) * 64) * K + (kt) * BK, &Bs[d][h][(q) * 4096 + t * 8])

  SA(0, 0, 0, 0); SA(0, 0, 1, 0); SA(0, 1, 0, 0); SA(0, 1, 1, 0);
  SB(0, 0, 0, 0); SB(0, 0, 1, 0); SB(0, 1, 0, 0); SB(0, 1, 1, 0);
  asm volatile("s_waitcnt vmcnt(0)" ::: "memory");
  BARRIER();

  const int ha = wr >> 1, ro = (wr & 1) * 64;

  for (int tt = 0; tt < NT; ++tt) {
    const int cur = tt & 1, nxt = cur ^ 1;
    const int ktn = tt + 1;
    const bool more = (ktn < NT);
    f16x8 a0[2][2], a1[2][2], b0[4][2], b1[4][2];

    // P1: read A-msub0 + B-set0; stage A half0
#pragma unroll
    for (int m = 0; m < 2; ++m) {
      const int r = (ro + m * 16 + fr) * 64;
      a0[m][0] = *((const f16x8*)(&As[cur][ha][r + cs0]));
      a0[m][1] = *((const f16x8*)(&As[cur][ha][r + cs1]));
    }
#pragma unroll
    for (int n = 0; n < 4; ++n) {
      const int r = (wc * 64 + n * 16 + fr) * 64;
      b0[n][0] = *((const f16x8*)(&Bs[cur][0][r + cs0]));
      b0[n][1] = *((const f16x8*)(&Bs[cur][0][r + cs1]));
    }
    if (more) { SA(nxt, 0, 0, ktn); SA(nxt, 0, 1, ktn); }
    BARRIER();
    __builtin_amdgcn_s_setprio(1);
#pragma unroll
    for (int m = 0; m < 2; ++m)
#pragma unroll
      for (int n = 0; n < 4; ++n)
#pragma unroll
        for (int kk = 0; kk < 2; ++kk)
          acc[m][n] = MFMA16(a0[m][kk], b0[n][kk], acc[m][n]);
    __builtin_amdgcn_s_setprio(0);
    if (more) asm volatile("s_waitcnt vmcnt(2)" ::: "memory");
    else      asm volatile("s_waitcnt vmcnt(0)" ::: "memory");
    BARRIER();

    // P2: read B-set1; stage A half1
#pragma unroll
    for (int n = 0; n < 4; ++n) {
      const int r = (wc * 64 + n * 16 + fr) * 64;
      b1[n][0] = *((const f16x8*)(&Bs[cur][1][r + cs0]));
      b1[n][1] = *((const f16x8*)(&Bs[cur][1][r + cs1]));
    }
    if (more) { SA(nxt, 1, 0, ktn); SA(nxt, 1, 1, ktn); }
    BARRIER();
    __builtin_amdgcn_s_setprio(1);
#pragma unroll
    for (int m = 0; m < 2; ++m)
#pragma unroll
      for (int n = 0; n < 4; ++n)
#pragma unroll
        for (int kk = 0; kk < 2; ++kk)
          acc[m][4 + n] = MFMA16(a0[m][kk], b1[n][kk], acc[m][4 + n]);
    __builtin_amdgcn_s_setprio(0);
    BARRIER();

    // P3: read A-msub1; stage B half0
#pragma unroll
    for (int m = 0; m < 2; ++m) {
      const int r = (ro + 32 + m * 16 + fr) * 64;
      a1[m][0] = *((const f16x8*)(&As[cur][ha][r + cs0]));
      a1[m][1] = *((const f16x8*)(&As[cur][ha][r + cs1]));
    }
    if (more) { SB(nxt, 0, 0, ktn); SB(nxt, 0, 1, ktn); }
    BARRIER();
    __builtin_amdgcn_s_setprio(1);
#pragma unroll
    for (int m = 0; m < 2; ++m)
#pragma unroll
      for (int n = 0; n < 4; ++n)
#pragma unroll
        for (int kk = 0; kk < 2; ++kk)
          acc[2 + m][4 + n] = MFMA16(a1[m][kk], b1[n][kk], acc[2 + m][4 + n]);
    __builtin_amdgcn_s_setprio(0);
    BARRIER();

    // P4: stage B half1; MFMA msub1 x set0 (a1, b0 still live)
    if (more) { SB(nxt, 1, 0, ktn); SB(nxt, 1, 1, ktn); }
    BARRIER();
    __builtin_amdgcn_s_setprio(1);
#pragma unroll
    for (int m = 0; m < 2; ++m)
#pragma unroll
      for (int n = 0; n < 4; ++n)
#pragma unroll
        for (int kk = 0; kk < 2; ++kk)
          acc[2 + m][n] = MFMA16(a1[m][kk], b0[n][kk], acc[2 + m][n]);
    __builtin_amdgcn_s_setprio(0);
    if (more) asm volatile("s_waitcnt vmcnt(2)" ::: "memory");
    BARRIER();
  }
#undef SA
#undef SB

#pragma unroll
  for (int s = 0; s < 2; ++s) {
#pragma unroll
    for (int n = 0; n < 4; ++n) {
      const int colg = bn0 + s * 128 + wc * 64 + n * 16 + fr;
      const float bias = bb[colg];
#pragma unroll
      for (int m = 0; m < 4; ++m)
#pragma unroll
        for (int i = 0; i < 4; ++i) {
          const int rowg = arow0 + wr * 64 + m * 16 + klo * 4 + i;
          float v = acc[m][s * 4 + n][i] + bias;
          v = 1.7159f * tanhf(0.666f * v);
          H[(size_t)rowg * UNITS_ + colg] = (f16)v;
        }
    }
  }
}

// ---- GEMM2: four heads fused, same template -----------------------------
// M=16384 N'=2048(head-interleaved) K=1024. Grid 64x8 = 512 blocks. NT=16.
// frag n == head; epilogue combines 4 heads thread-locally.

__global__ __launch_bounds__(512, 2) void gemm2_kernel(
    const f16* __restrict__ Hm, const f16* __restrict__ Wp,
    const float* __restrict__ b1, const float* __restrict__ b2,
    const float* __restrict__ ba, const float* __restrict__ bt,
    const float* __restrict__ ts, float* __restrict__ out) {
  constexpr int K = UNITS_, BK = 64, NT = K / BK;  // 16
  __shared__ f16 As[2][2][8192];
  __shared__ f16 Bs[2][2][8192];
  const int t = threadIdx.x;
  const int lane = t & 63, wid = t >> 6;
  const int wr = wid >> 1;          // 0..3
  const int wc = wid & 1;           // 0..1
  const int bc = blockIdx.x & 7, br = blockIdx.x >> 3;
  const int arow0 = br * 256;
  const int bn0 = bc * 256;

  f32x4 acc[4][8] = {};  // [m][set*4 + head]

  const int tr = t >> 3;
  const int sch = ((t & 7) ^ (tr & 7)) * 8;
  const f16* aSrc = Hm + (size_t)(arow0 + tr) * K + sch;
  const f16* bSrc = Wp + (size_t)(bn0 + tr) * K + sch;

  const int fr = lane & 15, klo = lane >> 4;
  const int cs0 = (klo ^ (fr & 7)) * 8;
  const int cs1 = ((klo + 4) ^ (fr & 7)) * 8;

#define SA(d, h, q, kt) gload_lds16(aSrc + (size_t)((h) * 128 + (q) * 64) * K + (kt) * BK, &As[d][h][(q) * 4096 + t * 8])
#define SB(d, h, q, kt) gload_lds16(bSrc + (size_t)((h) * 128 + (q) * 64) * K + (kt) * BK, &Bs[d][h][(q) * 4096 + t * 8])

  SA(0, 0, 0, 0); SA(0, 0, 1, 0); SA(0, 1, 0, 0); SA(0, 1, 1, 0);
  SB(0, 0, 0, 0); SB(0, 0, 1, 0); SB(0, 1, 0, 0); SB(0, 1, 1, 0);
  asm volatile("s_waitcnt vmcnt(0)" ::: "memory");
  BARRIER();

  const int ha = wr >> 1, ro = (wr & 1) * 64;

  for (int tt = 0; tt < NT; ++tt) {
    const int cur = tt & 1, nxt = cur ^ 1;
    const int ktn = tt + 1;
    const bool more = (ktn < NT);
    f16x8 a0[2][2], a1[2][2], b0[4][2], b1[4][2];

    // P1
#pragma unroll
    for (int m = 0; m < 2; ++m) {
      const int r = (ro + m * 16 + fr) * 64;
      a0[m][0] = *((const f16x8*)(&As[cur][ha][r + cs0]));
      a0[m][1] = *((const f16x8*)(&As[cur][ha][r + cs1]));
    }
#pragma unroll
    for (int n = 0; n < 4; ++n) {
      const int r = (wc * 64 + n * 16 + fr) * 64;
      b0[n][0] = *((const f16x8*)(&Bs[cur][0][r + cs0]));
      b0[n][1] = *((const f16x8*)(&Bs[cur][0][r + cs1]));
    }
    if (more) { SA(nxt, 0, 0, ktn); SA(nxt, 0, 1, ktn); }
    BARRIER();
    __builtin_amdgcn_s_setprio(1);
#pragma unroll
    for (int m = 0; m < 2; ++m)
#pragma unroll
      for (int n = 0; n < 4; ++n)
#pragma unroll
        for (int kk = 0; kk < 2; ++kk)
          acc[m][n] = MFMA16(a0[m][kk], b0[n][kk], acc[m][n]);
    __builtin_amdgcn_s_setprio(0);
    if (more) asm volatile("s_waitcnt vmcnt(2)" ::: "memory");
    else      asm volatile("s_waitcnt vmcnt(0)" ::: "memory");
    BARRIER();

    // P2
#pragma unroll
    for (int n = 0; n < 4; ++n) {
      const int r = (wc * 64 + n * 16 + fr) * 64;
      b1[n][0] = *((const f16x8*)(&Bs[cur][1][r + cs0]));
      b1[n][1] = *((const f16x8*)(&Bs[cur][1][r + cs1]));
    }
    if (more) { SA(nxt, 1, 0, ktn); SA(nxt, 1, 1, ktn); }
    BARRIER();
    __builtin_amdgcn_s_setprio(1);
#pragma unroll
    for (int m = 0; m < 2; ++m)
#pragma unroll
      for (int n = 0; n < 4; ++n)
#pragma unroll
        for (int kk = 0; kk < 2; ++kk)
          acc[m][4 + n] = MFMA16(a0[m][kk], b1[n][kk], acc[m][4 + n]);
    __builtin_amdgcn_s_setprio(0);
    BARRIER();

    // P3
#pragma unroll
    for (int m = 0; m < 2; ++m) {
      const int r = (ro + 32 + m * 16 + fr) * 64;
      a1[m][0] = *((const f16x8*)(&As[cur][ha][r + cs0]));
      a1[m][1] = *((const f16x8*)(&As[cur][ha][r + cs1]));
    }
    if (more) { SB(nxt, 0, 0, ktn); SB(nxt, 0, 1, ktn); }
    BARRIER();
    __builtin_amdgcn_s_setprio(1);
#pragma unroll
    for (int m = 0; m < 2; ++m)
#pragma unroll
      for (int n = 0; n < 4; ++n)
#pragma unroll
        for (int kk = 0; kk < 2; ++kk)
          acc[2 + m][4 + n] = MFMA16(a1[m][kk], b1[n][kk], acc[2 + m][4 + n]);
    __builtin_amdgcn_s_setprio(0);
    BARRIER();

    // P4
    if (more) { SB(nxt, 1, 0, ktn); SB(nxt, 1, 1, ktn); }
    BARRIER();
    __builtin_amdgcn_s_setprio(1);
#pragma unroll
    for (int m = 0; m < 2; ++m)
#pragma unroll
      for (int n = 0; n < 4; ++n)
#pragma unroll
        for (int kk = 0; kk < 2; ++kk)
          acc[2 + m][n] = MFMA16(a1[m][kk], b0[n][kk], acc[2 + m][n]);
    __builtin_amdgcn_s_setprio(0);
    if (more) asm volatile("s_waitcnt vmcnt(2)" ::: "memory");
    BARRIER();
  }
#undef SA
#undef SB

  // epilogue: set s, frag n == head; hidcol = (bc*4 + s*2 + wc)*16 + fr
#pragma unroll
  for (int s = 0; s < 2; ++s) {
    const int colg = (bc * 4 + s * 2 + wc) * 16 + fr;  // 0..511
    const float B1 = b1[colg], B2 = b2[colg], BA = ba[colg], BT = bt[colg];
#pragma unroll
    for (int m = 0; m < 4; ++m)
#pragma unroll
      for (int i = 0; i < 4; ++i) {
        const int rowg = arow0 + wr * 64 + m * 16 + klo * 4 + i;
        const float ff1 = tanhf(acc[m][s * 4 + 0][i] + B1);
        const float ff2 = tanhf(acc[m][s * 4 + 1][i] + B2);
        const float ta = acc[m][s * 4 + 2][i] + BA;
        const float tb = acc[m][s * 4 + 3][i] + BT;
        const float z = ta * ts[rowg] + tb;
        const float ti = 1.0f / (1.0f + __expf(-z));
        out[(size_t)rowg * HID_ + colg] = ff1 + ti * (ff2 - ff1);
      }
  }
}

// ---- launch -------------------------------------------------------------

extern "C" void kernel_launch(void* const* d_in, const int* in_sizes, int n_in,
                              void* d_out, int out_size, void* d_ws, size_t ws_size,
                              hipStream_t stream) {
  const float* input = (const float*)d_in[0];
  const float* hx    = (const float*)d_in[1];
  const float* ts    = (const float*)d_in[2];
  const float* Wb    = (const float*)d_in[3];
  const float* bb    = (const float*)d_in[4];
  const float* W1    = (const float*)d_in[5];
  const float* b1    = (const float*)d_in[6];
  const float* W2    = (const float*)d_in[7];
  const float* b2    = (const float*)d_in[8];
  const float* Wa    = (const float*)d_in[9];
  const float* ba    = (const float*)d_in[10];
  const float* Wt    = (const float*)d_in[11];
  const float* bt    = (const float*)d_in[12];
  float* out = (float*)d_out;

  char* ws = (char*)d_ws;
  f16* x_f16  = (f16*)ws;  ws += (size_t)B_ * CAT_ * 2;
  f16* h_f16  = (f16*)ws;  ws += (size_t)B_ * UNITS_ * 2;
  f16* Wb_f16 = (f16*)ws;  ws += (size_t)UNITS_ * CAT_ * 2;
  f16* Wh_f16 = (f16*)ws;  ws += (size_t)4 * HID_ * UNITS_ * 2;

  build_x_kernel<<<(B_ * (CAT_ / 4) + 255) / 256, 256, 0, stream>>>(input, hx, x_f16);
  cvt_all_kernel<<<dim3(2048, 2), 256, 0, stream>>>(Wb, W1, W2, Wa, Wt, Wb_f16, Wh_f16);

  gemm1_kernel<<<dim3(256), 512, 0, stream>>>(x_f16, Wb_f16, bb, h_f16);
  gemm2_kernel<<<dim3(512), 512, 0, stream>>>(h_f16, Wh_f16, b1, b2, ba, bt, ts, out);
}

// Round 9
// 145.180 us; speedup vs baseline: 6.9929x; 1.0907x over previous
//
#include <hip/hip_runtime.h>

// CfC cell, fp16-MFMA implementation.
//   h   = 1.7159*tanh(0.666*(concat(input,hx) @ Wb^T + bb))   [B,1024]
//   ff1 = tanh(h@W1^T+b1), ff2 = tanh(h@W2^T+b2)
//   t   = sigmoid((h@Wa^T+ba)*ts + (h@Wt^T+bt))
//   out = ff1 + t*(ff2-ff1)                                   [B,512]
// Round 9: r8 retry with the prep-kernel grid segmentation FIXED (r8 crash:
// Wb segment was 4x oversized with no bounds check -> OOB writes).
// Segments: [0,12288) build_x | [12288,13056) Wb | [13056,15104) Wh.
// GEMM cores identical to r7 (verified) + r8 bijective XCD-aware mapping.

typedef _Float16 f16;
typedef _Float16 f16x8 __attribute__((ext_vector_type(8)));
typedef _Float16 f16x4 __attribute__((ext_vector_type(4)));
typedef float f32x4 __attribute__((ext_vector_type(4)));

static constexpr int B_ = 16384, IN_ = 256, HID_ = 512, UNITS_ = 1024, CAT_ = 768;

__device__ __forceinline__ void gload_lds16(const void* g, void* l) {
  __builtin_amdgcn_global_load_lds(
      (const __attribute__((address_space(1))) void*)g,
      (__attribute__((address_space(3))) void*)l, 16, 0, 0);
}

#define MFMA16(a, b, c) __builtin_amdgcn_mfma_f32_16x16x32_f16((a), (b), (c), 0, 0, 0)
#define BARRIER() do { asm volatile("" ::: "memory"); __builtin_amdgcn_s_barrier(); asm volatile("" ::: "memory"); } while (0)

// ---- prep: build x=concat(input,hx) as f16; cast Wb; head-interleave Wh --
// build_x: 16384*192 f4-groups = 12288 blocks exact
// Wb cast: 1024*768/4 = 196608 f4   =   768 blocks exact
// Wh ilv : 2048*256  = 524288 f4    =  2048 blocks exact

__global__ void prep_kernel(const float* __restrict__ inp,
                            const float* __restrict__ hx,
                            const float* __restrict__ Wb,
                            const float* __restrict__ W1,
                            const float* __restrict__ W2,
                            const float* __restrict__ Wa,
                            const float* __restrict__ Wt,
                            f16* __restrict__ x,
                            f16* __restrict__ dWb, f16* __restrict__ dWh) {
  const int blk = blockIdx.x;
  if (blk < 12288) {
    const int gid = blk * 256 + threadIdx.x;       // < 16384*192 exact
    const int per_row = CAT_ / 4;                  // 192
    int b = gid / per_row, j = gid - b * per_row;
    float4 v;
    if (j < IN_ / 4) v = ((const float4*)(inp + (size_t)b * IN_))[j];
    else             v = ((const float4*)(hx  + (size_t)b * HID_))[j - IN_ / 4];
    f16x4 o = {(f16)v.x, (f16)v.y, (f16)v.z, (f16)v.w};
    *((f16x4*)(x + (size_t)b * CAT_ + j * 4)) = o;
  } else if (blk < 13056) {
    const int i = (blk - 12288) * 256 + threadIdx.x;  // < 196608 exact
    float4 v = ((const float4*)Wb)[i];
    f16x4 o = {(f16)v.x, (f16)v.y, (f16)v.z, (f16)v.w};
    ((f16x4*)dWb)[i] = o;
  } else {
    const int i = (blk - 13056) * 256 + threadIdx.x;  // < 524288 exact
    const int np = i >> 8;                   // n' row in [0,2048)
    const int k4 = i & 255;
    const int h = (np >> 4) & 3;
    const int c = ((np >> 6) << 4) | (np & 15);
    const float* srcs[4] = {W1, W2, Wa, Wt};
    float4 v = *((const float4*)(srcs[h] + (size_t)c * UNITS_ + k4 * 4));
    f16x4 o = {(f16)v.x, (f16)v.y, (f16)v.z, (f16)v.w};
    *((f16x4*)(dWh + (size_t)np * UNITS_ + k4 * 4)) = o;
  }
}

// ---- GEMM1: h = lecun_tanh(X @ Wb^T + bb) ------------------------------
// M=16384 N=1024 K=768. 256 blocks; XCD map: br = (bid>>5)*8 + (bid&7).

__global__ __launch_bounds__(512, 2) void gemm1_kernel(
    const f16* __restrict__ X, const f16* __restrict__ Wb,
    const float* __restrict__ bb, f16* __restrict__ H) {
  constexpr int K = CAT_, BK = 64, NT = K / BK;  // 12
  __shared__ f16 As[2][2][8192];  // [dbuf][half][128*64]
  __shared__ f16 Bs[2][2][8192];
  const int t = threadIdx.x;
  const int lane = t & 63, wid = t >> 6;
  const int wr = wid >> 1;          // 0..3 (64-row band)
  const int wc = wid & 1;           // 0..1
  // XCD-aware: blocks sharing br share bid%8 -> same XCD L2 caches A-tile
  const int bc = (blockIdx.x >> 3) & 3;
  const int br = (blockIdx.x >> 5) * 8 + (blockIdx.x & 7);
  const int arow0 = br * 256;
  const int bn0 = bc * 256;

  f32x4 acc[4][8] = {};  // [m 0..3][set*4 + n]

  const int tr = t >> 3;                         // 0..63
  const int sch = ((t & 7) ^ (tr & 7)) * 8;      // pre-swizzled src chunk
  const f16* aSrc = X + (size_t)(arow0 + tr) * K + sch;
  const f16* bSrc = Wb + (size_t)(bn0 + tr) * K + sch;

  const int fr = lane & 15, klo = lane >> 4;
  const int cs0 = (klo ^ (fr & 7)) * 8;          // kk=0 phys chunk (f16 off)
  const int cs1 = ((klo + 4) ^ (fr & 7)) * 8;    // kk=1

#define SA(d, h, q, kt) gload_lds16(aSrc + (size_t)((h) * 128 + (q) * 64) * K + (kt) * BK, &As[d][h][(q) * 4096 + t * 8])
#define SB(d, h, q, kt) gload_lds16(bSrc + (size_t)((h) * 128 + (q) * 64) * K + (kt) * BK, &Bs[d][h][(q) * 4096 + t * 8])

  SA(0, 0, 0, 0); SA(0, 0, 1, 0); SA(0, 1, 0, 0); SA(0, 1, 1, 0);
  SB(0, 0, 0, 0); SB(0, 0, 1, 0); SB(0, 1, 0, 0); SB(0, 1, 1, 0);
  asm volatile("s_waitcnt vmcnt(0)" ::: "memory");
  BARRIER();

  const int ha = wr >> 1, ro = (wr & 1) * 64;

  for (int tt = 0; tt < NT; ++tt) {
    const int cur = tt & 1, nxt = cur ^ 1;
    const int ktn = tt + 1;
    const bool more = (ktn < NT);
    f16x8 a0[2][2], a1[2][2], b0[4][2], b1[4][2];

    // P1: read A-msub0 + B-set0; stage A half0
#pragma unroll
    for (int m = 0; m < 2; ++m) {
      const int r = (ro + m * 16 + fr) * 64;
      a0[m][0] = *((const f16x8*)(&As[cur][ha][r + cs0]));
      a0[m][1] = *((const f16x8*)(&As[cur][ha][r + cs1]));
    }
#pragma unroll
    for (int n = 0; n < 4; ++n) {
      const int r = (wc * 64 + n * 16 + fr) * 64;
      b0[n][0] = *((const f16x8*)(&Bs[cur][0][r + cs0]));
      b0[n][1] = *((const f16x8*)(&Bs[cur][0][r + cs1]));
    }
    if (more) { SA(nxt, 0, 0, ktn); SA(nxt, 0, 1, ktn); }
    BARRIER();
    __builtin_amdgcn_s_setprio(1);
#pragma unroll
    for (int m = 0; m < 2; ++m)
#pragma unroll
      for (int n = 0; n < 4; ++n)
#pragma unroll
        for (int kk = 0; kk < 2; ++kk)
          acc[m][n] = MFMA16(a0[m][kk], b0[n][kk], acc[m][n]);
    __builtin_amdgcn_s_setprio(0);
    if (more) asm volatile("s_waitcnt vmcnt(2)" ::: "memory");
    else      asm volatile("s_waitcnt vmcnt(0)" ::: "memory");
    BARRIER();

    // P2: read B-set1; stage A half1
#pragma unroll
    for (int n = 0; n < 4; ++n) {
      const int r = (wc * 64 + n * 16 + fr) * 64;
      b1[n][0] = *((const f16x8*)(&Bs[cur][1][r + cs0]));
      b1[n][1] = *((const f16x8*)(&Bs[cur][1][r + cs1]));
    }
    if (more) { SA(nxt, 1, 0, ktn); SA(nxt, 1, 1, ktn); }
    BARRIER();
    __builtin_amdgcn_s_setprio(1);
#pragma unroll
    for (int m = 0; m < 2; ++m)
#pragma unroll
      for (int n = 0; n < 4; ++n)
#pragma unroll
        for (int kk = 0; kk < 2; ++kk)
          acc[m][4 + n] = MFMA16(a0[m][kk], b1[n][kk], acc[m][4 + n]);
    __builtin_amdgcn_s_setprio(0);
    BARRIER();

    // P3: read A-msub1; stage B half0
#pragma unroll
    for (int m = 0; m < 2; ++m) {
      const int r = (ro + 32 + m * 16 + fr) * 64;
      a1[m][0] = *((const f16x8*)(&As[cur][ha][r + cs0]));
      a1[m][1] = *((const f16x8*)(&As[cur][ha][r + cs1]));
    }
    if (more) { SB(nxt, 0, 0, ktn); SB(nxt, 0, 1, ktn); }
    BARRIER();
    __builtin_amdgcn_s_setprio(1);
#pragma unroll
    for (int m = 0; m < 2; ++m)
#pragma unroll
      for (int n = 0; n < 4; ++n)
#pragma unroll
        for (int kk = 0; kk < 2; ++kk)
          acc[2 + m][4 + n] = MFMA16(a1[m][kk], b1[n][kk], acc[2 + m][4 + n]);
    __builtin_amdgcn_s_setprio(0);
    BARRIER();

    // P4: stage B half1; MFMA msub1 x set0 (a1, b0 still live)
    if (more) { SB(nxt, 1, 0, ktn); SB(nxt, 1, 1, ktn); }
    BARRIER();
    __builtin_amdgcn_s_setprio(1);
#pragma unroll
    for (int m = 0; m < 2; ++m)
#pragma unroll
      for (int n = 0; n < 4; ++n)
#pragma unroll
        for (int kk = 0; kk < 2; ++kk)
          acc[2 + m][n] = MFMA16(a1[m][kk], b0[n][kk], acc[2 + m][n]);
    __builtin_amdgcn_s_setprio(0);
    if (more) asm volatile("s_waitcnt vmcnt(2)" ::: "memory");
    BARRIER();
  }
#undef SA
#undef SB

#pragma unroll
  for (int s = 0; s < 2; ++s) {
#pragma unroll
    for (int n = 0; n < 4; ++n) {
      const int colg = bn0 + s * 128 + wc * 64 + n * 16 + fr;
      const float bias = bb[colg];
#pragma unroll
      for (int m = 0; m < 4; ++m)
#pragma unroll
        for (int i = 0; i < 4; ++i) {
          const int rowg = arow0 + wr * 64 + m * 16 + klo * 4 + i;
          float v = acc[m][s * 4 + n][i] + bias;
          v = 1.7159f * tanhf(0.666f * v);
          H[(size_t)rowg * UNITS_ + colg] = (f16)v;
        }
    }
  }
}

// ---- GEMM2: four heads fused, same template -----------------------------
// M=16384 N'=2048(head-interleaved) K=1024. 512 blocks; XCD map:
// br = (bid>>6)*8 + (bid&7), bc = (bid>>3)&7.

__global__ __launch_bounds__(512, 2) void gemm2_kernel(
    const f16* __restrict__ Hm, const f16* __restrict__ Wp,
    const float* __restrict__ b1, const float* __restrict__ b2,
    const float* __restrict__ ba, const float* __restrict__ bt,
    const float* __restrict__ ts, float* __restrict__ out) {
  constexpr int K = UNITS_, BK = 64, NT = K / BK;  // 16
  __shared__ f16 As[2][2][8192];
  __shared__ f16 Bs[2][2][8192];
  const int t = threadIdx.x;
  const int lane = t & 63, wid = t >> 6;
  const int wr = wid >> 1;          // 0..3
  const int wc = wid & 1;           // 0..1
  const int bc = (blockIdx.x >> 3) & 7;
  const int br = (blockIdx.x >> 6) * 8 + (blockIdx.x & 7);
  const int arow0 = br * 256;
  const int bn0 = bc * 256;

  f32x4 acc[4][8] = {};  // [m][set*4 + head]

  const int tr = t >> 3;
  const int sch = ((t & 7) ^ (tr & 7)) * 8;
  const f16* aSrc = Hm + (size_t)(arow0 + tr) * K + sch;
  const f16* bSrc = Wp + (size_t)(bn0 + tr) * K + sch;

  const int fr = lane & 15, klo = lane >> 4;
  const int cs0 = (klo ^ (fr & 7)) * 8;
  const int cs1 = ((klo + 4) ^ (fr & 7)) * 8;

#define SA(d, h, q, kt) gload_lds16(aSrc + (size_t)((h) * 128 + (q) * 64) * K + (kt) * BK, &As[d][h][(q) * 4096 + t * 8])
#define SB(d, h, q, kt) gload_lds16(bSrc + (size_t)((h) * 128 + (q) * 64) * K + (kt) * BK, &Bs[d][h][(q) * 4096 + t * 8])

  SA(0, 0, 0, 0); SA(0, 0, 1, 0); SA(0, 1, 0, 0); SA(0, 1, 1, 0);
  SB(0, 0, 0, 0); SB(0, 0, 1, 0); SB(0, 1, 0, 0); SB(0, 1, 1, 0);
  asm volatile("s_waitcnt vmcnt(0)" ::: "memory");
  BARRIER();

  const int ha = wr >> 1, ro = (wr & 1) * 64;

  for (int tt = 0; tt < NT; ++tt) {
    const int cur = tt & 1, nxt = cur ^ 1;
    const int ktn = tt + 1;
    const bool more = (ktn < NT);
    f16x8 a0[2][2], a1[2][2], b0[4][2], b1[4][2];

    // P1
#pragma unroll
    for (int m = 0; m < 2; ++m) {
      const int r = (ro + m * 16 + fr) * 64;
      a0[m][0] = *((const f16x8*)(&As[cur][ha][r + cs0]));
      a0[m][1] = *((const f16x8*)(&As[cur][ha][r + cs1]));
    }
#pragma unroll
    for (int n = 0; n < 4; ++n) {
      const int r = (wc * 64 + n * 16 + fr) * 64;
      b0[n][0] = *((const f16x8*)(&Bs[cur][0][r + cs0]));
      b0[n][1] = *((const f16x8*)(&Bs[cur][0][r + cs1]));
    }
    if (more) { SA(nxt, 0, 0, ktn); SA(nxt, 0, 1, ktn); }
    BARRIER();
    __builtin_amdgcn_s_setprio(1);
#pragma unroll
    for (int m = 0; m < 2; ++m)
#pragma unroll
      for (int n = 0; n < 4; ++n)
#pragma unroll
        for (int kk = 0; kk < 2; ++kk)
          acc[m][n] = MFMA16(a0[m][kk], b0[n][kk], acc[m][n]);
    __builtin_amdgcn_s_setprio(0);
    if (more) asm volatile("s_waitcnt vmcnt(2)" ::: "memory");
    else      asm volatile("s_waitcnt vmcnt(0)" ::: "memory");
    BARRIER();

    // P2
#pragma unroll
    for (int n = 0; n < 4; ++n) {
      const int r = (wc * 64 + n * 16 + fr) * 64;
      b1[n][0] = *((const f16x8*)(&Bs[cur][1][r + cs0]));
      b1[n][1] = *((const f16x8*)(&Bs[cur][1][r + cs1]));
    }
    if (more) { SA(nxt, 1, 0, ktn); SA(nxt, 1, 1, ktn); }
    BARRIER();
    __builtin_amdgcn_s_setprio(1);
#pragma unroll
    for (int m = 0; m < 2; ++m)
#pragma unroll
      for (int n = 0; n < 4; ++n)
#pragma unroll
        for (int kk = 0; kk < 2; ++kk)
          acc[m][4 + n] = MFMA16(a0[m][kk], b1[n][kk], acc[m][4 + n]);
    __builtin_amdgcn_s_setprio(0);
    BARRIER();

    // P3
#pragma unroll
    for (int m = 0; m < 2; ++m) {
      const int r = (ro + 32 + m * 16 + fr) * 64;
      a1[m][0] = *((const f16x8*)(&As[cur][ha][r + cs0]));
      a1[m][1] = *((const f16x8*)(&As[cur][ha][r + cs1]));
    }
    if (more) { SB(nxt, 0, 0, ktn); SB(nxt, 0, 1, ktn); }
    BARRIER();
    __builtin_amdgcn_s_setprio(1);
#pragma unroll
    for (int m = 0; m < 2; ++m)
#pragma unroll
      for (int n = 0; n < 4; ++n)
#pragma unroll
        for (int kk = 0; kk < 2; ++kk)
          acc[2 + m][4 + n] = MFMA16(a1[m][kk], b1[n][kk], acc[2 + m][4 + n]);
    __builtin_amdgcn_s_setprio(0);
    BARRIER();

    // P4
    if (more) { SB(nxt, 1, 0, ktn); SB(nxt, 1, 1, ktn); }
    BARRIER();
    __builtin_amdgcn_s_setprio(1);
#pragma unroll
    for (int m = 0; m < 2; ++m)
#pragma unroll
      for (int n = 0; n < 4; ++n)
#pragma unroll
        for (int kk = 0; kk < 2; ++kk)
          acc[2 + m][n] = MFMA16(a1[m][kk], b0[n][kk], acc[2 + m][n]);
    __builtin_amdgcn_s_setprio(0);
    if (more) asm volatile("s_waitcnt vmcnt(2)" ::: "memory");
    BARRIER();
  }
#undef SA
#undef SB

  // epilogue: set s, frag n == head; hidcol = (bc*4 + s*2 + wc)*16 + fr
#pragma unroll
  for (int s = 0; s < 2; ++s) {
    const int colg = (bc * 4 + s * 2 + wc) * 16 + fr;  // 0..511
    const float B1 = b1[colg], B2 = b2[colg], BA = ba[colg], BT = bt[colg];
#pragma unroll
    for (int m = 0; m < 4; ++m)
#pragma unroll
      for (int i = 0; i < 4; ++i) {
        const int rowg = arow0 + wr * 64 + m * 16 + klo * 4 + i;
        const float ff1 = tanhf(acc[m][s * 4 + 0][i] + B1);
        const float ff2 = tanhf(acc[m][s * 4 + 1][i] + B2);
        const float ta = acc[m][s * 4 + 2][i] + BA;
        const float tb = acc[m][s * 4 + 3][i] + BT;
        const float z = ta * ts[rowg] + tb;
        const float ti = 1.0f / (1.0f + __expf(-z));
        out[(size_t)rowg * HID_ + colg] = ff1 + ti * (ff2 - ff1);
      }
  }
}

// ---- launch -------------------------------------------------------------

extern "C" void kernel_launch(void* const* d_in, const int* in_sizes, int n_in,
                              void* d_out, int out_size, void* d_ws, size_t ws_size,
                              hipStream_t stream) {
  const float* input = (const float*)d_in[0];
  const float* hx    = (const float*)d_in[1];
  const float* ts    = (const float*)d_in[2];
  const float* Wb    = (const float*)d_in[3];
  const float* bb    = (const float*)d_in[4];
  const float* W1    = (const float*)d_in[5];
  const float* b1    = (const float*)d_in[6];
  const float* W2    = (const float*)d_in[7];
  const float* b2    = (const float*)d_in[8];
  const float* Wa    = (const float*)d_in[9];
  const float* ba    = (const float*)d_in[10];
  const float* Wt    = (const float*)d_in[11];
  const float* bt    = (const float*)d_in[12];
  float* out = (float*)d_out;

  char* ws = (char*)d_ws;
  f16* x_f16  = (f16*)ws;  ws += (size_t)B_ * CAT_ * 2;
  f16* h_f16  = (f16*)ws;  ws += (size_t)B_ * UNITS_ * 2;
  f16* Wb_f16 = (f16*)ws;  ws += (size_t)UNITS_ * CAT_ * 2;
  f16* Wh_f16 = (f16*)ws;  ws += (size_t)4 * HID_ * UNITS_ * 2;

  prep_kernel<<<dim3(15104), 256, 0, stream>>>(input, hx, Wb, W1, W2, Wa, Wt,
                                               x_f16, Wb_f16, Wh_f16);
  gemm1_kernel<<<dim3(256), 512, 0, stream>>>(x_f16, Wb_f16, bb, h_f16);
  gemm2_kernel<<<dim3(512), 512, 0, stream>>>(h_f16, Wh_f16, b1, b2, ba, bt, ts, out);
}

// Round 10
// 136.524 us; speedup vs baseline: 7.4362x; 1.0634x over previous
//
#include <hip/hip_runtime.h>

// CfC cell, fp16-MFMA implementation.
//   h   = 1.7159*tanh(0.666*(concat(input,hx) @ Wb^T + bb))   [B,1024]
//   ff1 = tanh(h@W1^T+b1), ff2 = tanh(h@W2^T+b2)
//   t   = sigmoid((h@Wa^T+ba)*ts + (h@Wt^T+bt))
//   out = ff1 + t*(ff2-ff1)                                   [B,512]
// Round 10: single-barrier K-tile. r9's 4-phase lockstep made LDS-drain and
// MFMA windows additive (8 barriers/K-tile); the double buffer makes ONE
// barrier per K-tile sufficient (stages for t+1 write buf[nxt]; a wave
// reaches t+1's stages-into-buf[cur] only after the tile-t barrier, by which
// time all waves' reads retired). New tile: issue 20 ds_reads -> issue all
// 8 gload_lds(t+1) -> MFMA c1 -> read a1 -> MFMA c2,c3,c4 -> vmcnt(0)+bar.
// Compiler's fine-grained lgkmcnt overlaps LDS drain with MFMA clusters.
// Indexing/swizzle/XCD-map/epilogue identical to r9 (verified).

typedef _Float16 f16;
typedef _Float16 f16x8 __attribute__((ext_vector_type(8)));
typedef _Float16 f16x4 __attribute__((ext_vector_type(4)));
typedef float f32x4 __attribute__((ext_vector_type(4)));

static constexpr int B_ = 16384, IN_ = 256, HID_ = 512, UNITS_ = 1024, CAT_ = 768;

__device__ __forceinline__ void gload_lds16(const void* g, void* l) {
  __builtin_amdgcn_global_load_lds(
      (const __attribute__((address_space(1))) void*)g,
      (__attribute__((address_space(3))) void*)l, 16, 0, 0);
}

#define MFMA16(a, b, c) __builtin_amdgcn_mfma_f32_16x16x32_f16((a), (b), (c), 0, 0, 0)
#define BARRIER() do { asm volatile("" ::: "memory"); __builtin_amdgcn_s_barrier(); asm volatile("" ::: "memory"); } while (0)

// ---- prep: build x=concat(input,hx) as f16; cast Wb; head-interleave Wh --
// [0,12288) build_x | [12288,13056) Wb | [13056,15104) Wh   (all exact)

__global__ void prep_kernel(const float* __restrict__ inp,
                            const float* __restrict__ hx,
                            const float* __restrict__ Wb,
                            const float* __restrict__ W1,
                            const float* __restrict__ W2,
                            const float* __restrict__ Wa,
                            const float* __restrict__ Wt,
                            f16* __restrict__ x,
                            f16* __restrict__ dWb, f16* __restrict__ dWh) {
  const int blk = blockIdx.x;
  if (blk < 12288) {
    const int gid = blk * 256 + threadIdx.x;       // < 16384*192 exact
    const int per_row = CAT_ / 4;                  // 192
    int b = gid / per_row, j = gid - b * per_row;
    float4 v;
    if (j < IN_ / 4) v = ((const float4*)(inp + (size_t)b * IN_))[j];
    else             v = ((const float4*)(hx  + (size_t)b * HID_))[j - IN_ / 4];
    f16x4 o = {(f16)v.x, (f16)v.y, (f16)v.z, (f16)v.w};
    *((f16x4*)(x + (size_t)b * CAT_ + j * 4)) = o;
  } else if (blk < 13056) {
    const int i = (blk - 12288) * 256 + threadIdx.x;  // < 196608 exact
    float4 v = ((const float4*)Wb)[i];
    f16x4 o = {(f16)v.x, (f16)v.y, (f16)v.z, (f16)v.w};
    ((f16x4*)dWb)[i] = o;
  } else {
    const int i = (blk - 13056) * 256 + threadIdx.x;  // < 524288 exact
    const int np = i >> 8;                   // n' row in [0,2048)
    const int k4 = i & 255;
    const int h = (np >> 4) & 3;
    const int c = ((np >> 6) << 4) | (np & 15);
    const float* srcs[4] = {W1, W2, Wa, Wt};
    float4 v = *((const float4*)(srcs[h] + (size_t)c * UNITS_ + k4 * 4));
    f16x4 o = {(f16)v.x, (f16)v.y, (f16)v.z, (f16)v.w};
    *((f16x4*)(dWh + (size_t)np * UNITS_ + k4 * 4)) = o;
  }
}

// ---- GEMM1: h = lecun_tanh(X @ Wb^T + bb) ------------------------------
// M=16384 N=1024 K=768. 256 blocks; XCD map: br = (bid>>5)*8 + (bid&7).

__global__ __launch_bounds__(512, 2) void gemm1_kernel(
    const f16* __restrict__ X, const f16* __restrict__ Wb,
    const float* __restrict__ bb, f16* __restrict__ H) {
  constexpr int K = CAT_, BK = 64, NT = K / BK;  // 12
  __shared__ f16 As[2][2][8192];  // [dbuf][half][128*64]
  __shared__ f16 Bs[2][2][8192];
  const int t = threadIdx.x;
  const int lane = t & 63, wid = t >> 6;
  const int wr = wid >> 1;          // 0..3 (64-row band)
  const int wc = wid & 1;           // 0..1
  const int bc = (blockIdx.x >> 3) & 3;
  const int br = (blockIdx.x >> 5) * 8 + (blockIdx.x & 7);
  const int arow0 = br * 256;
  const int bn0 = bc * 256;

  f32x4 acc[4][8] = {};  // [m 0..3][set*4 + n]

  const int tr = t >> 3;                         // 0..63
  const int sch = ((t & 7) ^ (tr & 7)) * 8;      // pre-swizzled src chunk
  const f16* aSrc = X + (size_t)(arow0 + tr) * K + sch;
  const f16* bSrc = Wb + (size_t)(bn0 + tr) * K + sch;

  const int fr = lane & 15, klo = lane >> 4;
  const int cs0 = (klo ^ (fr & 7)) * 8;          // kk=0 phys chunk (f16 off)
  const int cs1 = ((klo + 4) ^ (fr & 7)) * 8;    // kk=1

#define SA(d, h, q, kt) gload_lds16(aSrc + (size_t)((h) * 128 + (q) * 64) * K + (kt) * BK, &As[d][h][(q) * 4096 + t * 8])
#define SB(d, h, q, kt) gload_lds16(bSrc + (size_t)((h) * 128 + (q) * 64) * K + (kt) * BK, &Bs[d][h][(q) * 4096 + t * 8])

  SA(0, 0, 0, 0); SA(0, 0, 1, 0); SA(0, 1, 0, 0); SA(0, 1, 1, 0);
  SB(0, 0, 0, 0); SB(0, 0, 1, 0); SB(0, 1, 0, 0); SB(0, 1, 1, 0);
  asm volatile("s_waitcnt vmcnt(0)" ::: "memory");
  BARRIER();

  const int ha = wr >> 1, ro = (wr & 1) * 64;

  for (int tt = 0; tt < NT; ++tt) {
    const int cur = tt & 1, nxt = cur ^ 1;
    const int ktn = tt + 1;
    const bool more = (ktn < NT);
    f16x8 a0[2][2], a1[2][2], b0[4][2], b1[4][2];

    // issue reads: a0 (4), b0 (8), b1 (8)
#pragma unroll
    for (int m = 0; m < 2; ++m) {
      const int r = (ro + m * 16 + fr) * 64;
      a0[m][0] = *((const f16x8*)(&As[cur][ha][r + cs0]));
      a0[m][1] = *((const f16x8*)(&As[cur][ha][r + cs1]));
    }
#pragma unroll
    for (int n = 0; n < 4; ++n) {
      const int r = (wc * 64 + n * 16 + fr) * 64;
      b0[n][0] = *((const f16x8*)(&Bs[cur][0][r + cs0]));
      b0[n][1] = *((const f16x8*)(&Bs[cur][0][r + cs1]));
    }
#pragma unroll
    for (int n = 0; n < 4; ++n) {
      const int r = (wc * 64 + n * 16 + fr) * 64;
      b1[n][0] = *((const f16x8*)(&Bs[cur][1][r + cs0]));
      b1[n][1] = *((const f16x8*)(&Bs[cur][1][r + cs1]));
    }
    // issue all next-tile stages early (latency hidden under this tile)
    if (more) {
      SA(nxt, 0, 0, ktn); SA(nxt, 0, 1, ktn); SA(nxt, 1, 0, ktn); SA(nxt, 1, 1, ktn);
      SB(nxt, 0, 0, ktn); SB(nxt, 0, 1, ktn); SB(nxt, 1, 0, ktn); SB(nxt, 1, 1, ktn);
    }
    // cluster 1: a0 x b0
    __builtin_amdgcn_s_setprio(1);
#pragma unroll
    for (int m = 0; m < 2; ++m)
#pragma unroll
      for (int n = 0; n < 4; ++n)
#pragma unroll
        for (int kk = 0; kk < 2; ++kk)
          acc[m][n] = MFMA16(a0[m][kk], b0[n][kk], acc[m][n]);
    __builtin_amdgcn_s_setprio(0);
    // issue a1 reads (after c1 to cap live VGPRs)
#pragma unroll
    for (int m = 0; m < 2; ++m) {
      const int r = (ro + 32 + m * 16 + fr) * 64;
      a1[m][0] = *((const f16x8*)(&As[cur][ha][r + cs0]));
      a1[m][1] = *((const f16x8*)(&As[cur][ha][r + cs1]));
    }
    // cluster 2: a0 x b1
    __builtin_amdgcn_s_setprio(1);
#pragma unroll
    for (int m = 0; m < 2; ++m)
#pragma unroll
      for (int n = 0; n < 4; ++n)
#pragma unroll
        for (int kk = 0; kk < 2; ++kk)
          acc[m][4 + n] = MFMA16(a0[m][kk], b1[n][kk], acc[m][4 + n]);
    // cluster 3: a1 x b1
#pragma unroll
    for (int m = 0; m < 2; ++m)
#pragma unroll
      for (int n = 0; n < 4; ++n)
#pragma unroll
        for (int kk = 0; kk < 2; ++kk)
          acc[2 + m][4 + n] = MFMA16(a1[m][kk], b1[n][kk], acc[2 + m][4 + n]);
    // cluster 4: a1 x b0
#pragma unroll
    for (int m = 0; m < 2; ++m)
#pragma unroll
      for (int n = 0; n < 4; ++n)
#pragma unroll
        for (int kk = 0; kk < 2; ++kk)
          acc[2 + m][n] = MFMA16(a1[m][kk], b0[n][kk], acc[2 + m][n]);
    __builtin_amdgcn_s_setprio(0);
    if (more) {
      asm volatile("s_waitcnt vmcnt(0)" ::: "memory");
      BARRIER();
    }
  }
#undef SA
#undef SB

#pragma unroll
  for (int s = 0; s < 2; ++s) {
#pragma unroll
    for (int n = 0; n < 4; ++n) {
      const int colg = bn0 + s * 128 + wc * 64 + n * 16 + fr;
      const float bias = bb[colg];
#pragma unroll
      for (int m = 0; m < 4; ++m)
#pragma unroll
        for (int i = 0; i < 4; ++i) {
          const int rowg = arow0 + wr * 64 + m * 16 + klo * 4 + i;
          float v = acc[m][s * 4 + n][i] + bias;
          v = 1.7159f * tanhf(0.666f * v);
          H[(size_t)rowg * UNITS_ + colg] = (f16)v;
        }
    }
  }
}

// ---- GEMM2: four heads fused, same single-barrier template --------------
// M=16384 N'=2048(head-interleaved) K=1024. 512 blocks; XCD map:
// br = (bid>>6)*8 + (bid&7), bc = (bid>>3)&7.

__global__ __launch_bounds__(512, 2) void gemm2_kernel(
    const f16* __restrict__ Hm, const f16* __restrict__ Wp,
    const float* __restrict__ b1, const float* __restrict__ b2,
    const float* __restrict__ ba, const float* __restrict__ bt,
    const float* __restrict__ ts, float* __restrict__ out) {
  constexpr int K = UNITS_, BK = 64, NT = K / BK;  // 16
  __shared__ f16 As[2][2][8192];
  __shared__ f16 Bs[2][2][8192];
  const int t = threadIdx.x;
  const int lane = t & 63, wid = t >> 6;
  const int wr = wid >> 1;          // 0..3
  const int wc = wid & 1;           // 0..1
  const int bc = (blockIdx.x >> 3) & 7;
  const int br = (blockIdx.x >> 6) * 8 + (blockIdx.x & 7);
  const int arow0 = br * 256;
  const int bn0 = bc * 256;

  f32x4 acc[4][8] = {};  // [m][set*4 + head]

  const int tr = t >> 3;
  const int sch = ((t & 7) ^ (tr & 7)) * 8;
  const f16* aSrc = Hm + (size_t)(arow0 + tr) * K + sch;
  const f16* bSrc = Wp + (size_t)(bn0 + tr) * K + sch;

  const int fr = lane & 15, klo = lane >> 4;
  const int cs0 = (klo ^ (fr & 7)) * 8;
  const int cs1 = ((klo + 4) ^ (fr & 7)) * 8;

#define SA(d, h, q, kt) gload_lds16(aSrc + (size_t)((h) * 128 + (q) * 64) * K + (kt) * BK, &As[d][h][(q) * 4096 + t * 8])
#define SB(d, h, q, kt) gload_lds16(bSrc + (size_t)((h) * 128 + (q) * 64) * K + (kt) * BK, &Bs[d][h][(q) * 4096 + t * 8])

  SA(0, 0, 0, 0); SA(0, 0, 1, 0); SA(0, 1, 0, 0); SA(0, 1, 1, 0);
  SB(0, 0, 0, 0); SB(0, 0, 1, 0); SB(0, 1, 0, 0); SB(0, 1, 1, 0);
  asm volatile("s_waitcnt vmcnt(0)" ::: "memory");
  BARRIER();

  const int ha = wr >> 1, ro = (wr & 1) * 64;

  for (int tt = 0; tt < NT; ++tt) {
    const int cur = tt & 1, nxt = cur ^ 1;
    const int ktn = tt + 1;
    const bool more = (ktn < NT);
    f16x8 a0[2][2], a1[2][2], b0[4][2], b1[4][2];

#pragma unroll
    for (int m = 0; m < 2; ++m) {
      const int r = (ro + m * 16 + fr) * 64;
      a0[m][0] = *((const f16x8*)(&As[cur][ha][r + cs0]));
      a0[m][1] = *((const f16x8*)(&As[cur][ha][r + cs1]));
    }
#pragma unroll
    for (int n = 0; n < 4; ++n) {
      const int r = (wc * 64 + n * 16 + fr) * 64;
      b0[n][0] = *((const f16x8*)(&Bs[cur][0][r + cs0]));
      b0[n][1] = *((const f16x8*)(&Bs[cur][0][r + cs1]));
    }
#pragma unroll
    for (int n = 0; n < 4; ++n) {
      const int r = (wc * 64 + n * 16 + fr) * 64;
      b1[n][0] = *((const f16x8*)(&Bs[cur][1][r + cs0]));
      b1[n][1] = *((const f16x8*)(&Bs[cur][1][r + cs1]));
    }
    if (more) {
      SA(nxt, 0, 0, ktn); SA(nxt, 0, 1, ktn); SA(nxt, 1, 0, ktn); SA(nxt, 1, 1, ktn);
      SB(nxt, 0, 0, ktn); SB(nxt, 0, 1, ktn); SB(nxt, 1, 0, ktn); SB(nxt, 1, 1, ktn);
    }
    __builtin_amdgcn_s_setprio(1);
#pragma unroll
    for (int m = 0; m < 2; ++m)
#pragma unroll
      for (int n = 0; n < 4; ++n)
#pragma unroll
        for (int kk = 0; kk < 2; ++kk)
          acc[m][n] = MFMA16(a0[m][kk], b0[n][kk], acc[m][n]);
    __builtin_amdgcn_s_setprio(0);
#pragma unroll
    for (int m = 0; m < 2; ++m) {
      const int r = (ro + 32 + m * 16 + fr) * 64;
      a1[m][0] = *((const f16x8*)(&As[cur][ha][r + cs0]));
      a1[m][1] = *((const f16x8*)(&As[cur][ha][r + cs1]));
    }
    __builtin_amdgcn_s_setprio(1);
#pragma unroll
    for (int m = 0; m < 2; ++m)
#pragma unroll
      for (int n = 0; n < 4; ++n)
#pragma unroll
        for (int kk = 0; kk < 2; ++kk)
          acc[m][4 + n] = MFMA16(a0[m][kk], b1[n][kk], acc[m][4 + n]);
#pragma unroll
    for (int m = 0; m < 2; ++m)
#pragma unroll
      for (int n = 0; n < 4; ++n)
#pragma unroll
        for (int kk = 0; kk < 2; ++kk)
          acc[2 + m][4 + n] = MFMA16(a1[m][kk], b1[n][kk], acc[2 + m][4 + n]);
#pragma unroll
    for (int m = 0; m < 2; ++m)
#pragma unroll
      for (int n = 0; n < 4; ++n)
#pragma unroll
        for (int kk = 0; kk < 2; ++kk)
          acc[2 + m][n] = MFMA16(a1[m][kk], b0[n][kk], acc[2 + m][n]);
    __builtin_amdgcn_s_setprio(0);
    if (more) {
      asm volatile("s_waitcnt vmcnt(0)" ::: "memory");
      BARRIER();
    }
  }
#undef SA
#undef SB

  // epilogue: set s, frag n == head; hidcol = (bc*4 + s*2 + wc)*16 + fr
#pragma unroll
  for (int s = 0; s < 2; ++s) {
    const int colg = (bc * 4 + s * 2 + wc) * 16 + fr;  // 0..511
    const float B1 = b1[colg], B2 = b2[colg], BA = ba[colg], BT = bt[colg];
#pragma unroll
    for (int m = 0; m < 4; ++m)
#pragma unroll
      for (int i = 0; i < 4; ++i) {
        const int rowg = arow0 + wr * 64 + m * 16 + klo * 4 + i;
        const float ff1 = tanhf(acc[m][s * 4 + 0][i] + B1);
        const float ff2 = tanhf(acc[m][s * 4 + 1][i] + B2);
        const float ta = acc[m][s * 4 + 2][i] + BA;
        const float tb = acc[m][s * 4 + 3][i] + BT;
        const float z = ta * ts[rowg] + tb;
        const float ti = 1.0f / (1.0f + __expf(-z));
        out[(size_t)rowg * HID_ + colg] = ff1 + ti * (ff2 - ff1);
      }
  }
}

// ---- launch -------------------------------------------------------------

extern "C" void kernel_launch(void* const* d_in, const int* in_sizes, int n_in,
                              void* d_out, int out_size, void* d_ws, size_t ws_size,
                              hipStream_t stream) {
  const float* input = (const float*)d_in[0];
  const float* hx    = (const float*)d_in[1];
  const float* ts    = (const float*)d_in[2];
  const float* Wb    = (const float*)d_in[3];
  const float* bb    = (const float*)d_in[4];
  const float* W1    = (const float*)d_in[5];
  const float* b1    = (const float*)d_in[6];
  const float* W2    = (const float*)d_in[7];
  const float* b2    = (const float*)d_in[8];
  const float* Wa    = (const float*)d_in[9];
  const float* ba    = (const float*)d_in[10];
  const float* Wt    = (const float*)d_in[11];
  const float* bt    = (const float*)d_in[12];
  float* out = (float*)d_out;

  char* ws = (char*)d_ws;
  f16* x_f16  = (f16*)ws;  ws += (size_t)B_ * CAT_ * 2;
  f16* h_f16  = (f16*)ws;  ws += (size_t)B_ * UNITS_ * 2;
  f16* Wb_f16 = (f16*)ws;  ws += (size_t)UNITS_ * CAT_ * 2;
  f16* Wh_f16 = (f16*)ws;  ws += (size_t)4 * HID_ * UNITS_ * 2;

  prep_kernel<<<dim3(15104), 256, 0, stream>>>(input, hx, Wb, W1, W2, Wa, Wt,
                                               x_f16, Wb_f16, Wh_f16);
  gemm1_kernel<<<dim3(256), 512, 0, stream>>>(x_f16, Wb_f16, bb, h_f16);
  gemm2_kernel<<<dim3(512), 512, 0, stream>>>(h_f16, Wh_f16, b1, b2, ba, bt, ts, out);
}